// Round 10
// baseline (102.756 us; speedup 1.0000x reference)
//
#include <hip/hip_runtime.h>

// SoftSmoothAP on MI355X. B=384, C=48, D=512. Output: scalar f32 loss = 1 - AP.
//
//   simk[i,q] = <preds_i, preds_q> * 100*log2(e)        (pre-scaled)
//   v(p,q) = 1/(1+exp2(simk[i,p] - simk[i,q]))          (= sigmoid(100(sim_q-sim_p)))
//   denom[i,p]  = 0.5 + sum_all_q v
//   W(p,q) = sum_{c in S_p & S_q} wsl[i,c],  wsl[i,c] = w[c]*softlabels[i,c]
//   loss = 1 - (1/B) sum_{i,p} inv_denom * (sum_q v*W(p,q) + 0.5*W(p,p))
//
// R10: phase B eliminated. The positive-rank numerators are folded into the
// denominator q-scan via 48-bit class-mask intersection (avg 0.47 shared
// classes/pair -> ~2 extra VALU per q on the idle VALU pipe). Cuts total
// sigmoids 83M -> 57M and removes all entry-list machinery.

#define BB 384
#define CC 48
#define DD 512
#define HALF 192
#define SCALE 144.269504089f  // 100 * log2(e)

__device__ __forceinline__ float sigm_pre(float x) {
    return __builtin_amdgcn_rcpf(1.0f + __builtin_amdgcn_exp2f(x));
}

// ---- 1. sim rows (blocks 0..191, 2 rows each) + prep (block 192) -------------
__global__ __launch_bounds__(384) void simprep_kernel(
    const float* __restrict__ preds, const float* __restrict__ softlabels,
    float* __restrict__ simk, float* __restrict__ wclass,
    uint2* __restrict__ maskbuf, float* __restrict__ out) {
    int tid = threadIdx.x;
    int wave = tid >> 6, lane = tid & 63;

    if (blockIdx.x < BB / 2) {
        // ---- sim: 2 rows per block, pre-scaled ----
        int i0 = blockIdx.x * 2;
        __shared__ __align__(16) float4 rows[2][DD / 4];
        const float4* src = reinterpret_cast<const float4*>(preds + i0 * DD);
        for (int v = tid; v < 2 * DD / 4; v += 384) (&rows[0][0])[v] = src[v];
        __syncthreads();
        int q = tid;
        const float4* pq = reinterpret_cast<const float4*>(preds + q * DD);
        float a0 = 0.f, a1 = 0.f;
#pragma unroll 8
        for (int d4 = 0; d4 < DD / 4; ++d4) {
            float4 b = pq[d4];
            float4 r0 = rows[0][d4];
            float4 r1 = rows[1][d4];
            a0 += r0.x * b.x + r0.y * b.y + r0.z * b.z + r0.w * b.w;
            a1 += r1.x * b.x + r1.y * b.y + r1.z * b.z + r1.w * b.w;
        }
        simk[i0 * BB + q] = a0 * SCALE;
        simk[(i0 + 1) * BB + q] = a1 * SCALE;
    } else {
        // ---- prep: per-row 48-bit positivity masks + per-class weights ----
        __shared__ unsigned int s_mlo[BB];
        __shared__ unsigned int s_mhi[BB];
        {
            const float4* row = reinterpret_cast<const float4*>(softlabels + tid * CC);
            unsigned int lo = 0, hi = 0;
#pragma unroll
            for (int v = 0; v < 12; ++v) {
                float4 x = row[v];
                unsigned int b = (x.x > 0.f ? 1u : 0u) | (x.y > 0.f ? 2u : 0u) |
                                 (x.z > 0.f ? 4u : 0u) | (x.w > 0.f ? 8u : 0u);
                if (v < 8) lo |= b << (4 * v);
                else       hi |= b << (4 * (v - 8));
            }
            s_mlo[tid] = lo;
            s_mhi[tid] = hi;
            maskbuf[tid] = make_uint2(lo, hi);
        }
        __syncthreads();
        // counts: wave w owns classes w*8..w*8+7; lanes sum p-strided bits
#pragma unroll
        for (int j = 0; j < 8; ++j) {
            int c = wave * 8 + j;
            int cnt = 0;
#pragma unroll
            for (int t = 0; t < BB / 64; ++t) {
                int p = t * 64 + lane;
                unsigned mb = (c < 32) ? s_mlo[p] : s_mhi[p];
                cnt += (mb >> (c & 31)) & 1u;
            }
            for (int off = 32; off > 0; off >>= 1) cnt += __shfl_down(cnt, off, 64);
            if (lane == 0) wclass[c] = (cnt >= 4) ? (1.0f / (float)cnt) : 0.0f;
        }
        if (tid == 0) out[0] = 1.0f;
    }
}

// ---- 2. mega768: fused denom + weighted-numerator scan, block = (i, h) -------
__global__ __launch_bounds__(384) void mega_kernel(
    const float* __restrict__ simk, const float* __restrict__ softlabels,
    const float* __restrict__ wclass, const uint2* __restrict__ maskbuf,
    float* __restrict__ out) {
    int i = blockIdx.x >> 1, h = blockIdx.x & 1;
    int tid = threadIdx.x;
    int wave = tid >> 6, lane = tid & 63;

    __shared__ __align__(16) float s_simk[BB];
    __shared__ uint2 s_mq[BB];
    __shared__ float s_wsl[CC];
    __shared__ float s_acc[384];
    __shared__ float s_wacc[384];
    __shared__ float s_red[6];

    s_simk[tid] = simk[i * BB + tid];
    s_mq[tid] = maskbuf[tid];
    if (tid < CC) s_wsl[tid] = wclass[tid] * softlabels[i * CC + tid];
    __syncthreads();

    int pl = tid % HALF;     // lane-contiguous p
    int chunk = tid / HALF;  // wave-uniform q-half
    int p = h * HALF + pl;
    float sp = s_simk[p];
    unsigned long long mp =
        ((unsigned long long)s_mq[p].y << 32) | (unsigned long long)s_mq[p].x;

    const float4* sv = reinterpret_cast<const float4*>(s_simk + chunk * HALF);
    int qbase = chunk * HALF;
    float a0 = 0.f, a1 = 0.f, a2 = 0.f, a3 = 0.f;
    float wacc = 0.f;
#pragma unroll 2
    for (int t = 0; t < HALF / 4; ++t) {
        float4 v4 = sv[t];  // wave-uniform broadcast read
        float v0 = sigm_pre(sp - v4.x);
        float v1 = sigm_pre(sp - v4.y);
        float v2 = sigm_pre(sp - v4.z);
        float v3 = sigm_pre(sp - v4.w);
        a0 += v0; a1 += v1; a2 += v2; a3 += v3;
        if (mp) {  // lane-invariant across t; masked lanes skip the W part
            int qb = qbase + 4 * t;
            uint2 u0 = s_mq[qb + 0];  // uniform broadcast reads
            uint2 u1 = s_mq[qb + 1];
            uint2 u2 = s_mq[qb + 2];
            uint2 u3 = s_mq[qb + 3];
            unsigned long long m0 = (((unsigned long long)u0.y << 32) | u0.x) & mp;
            unsigned long long m1 = (((unsigned long long)u1.y << 32) | u1.x) & mp;
            unsigned long long m2 = (((unsigned long long)u2.y << 32) | u2.x) & mp;
            unsigned long long m3 = (((unsigned long long)u3.y << 32) | u3.x) & mp;
            while (m0) { int c = __builtin_ctzll(m0); wacc += v0 * s_wsl[c]; m0 &= m0 - 1; }
            while (m1) { int c = __builtin_ctzll(m1); wacc += v1 * s_wsl[c]; m1 &= m1 - 1; }
            while (m2) { int c = __builtin_ctzll(m2); wacc += v2 * s_wsl[c]; m2 &= m2 - 1; }
            while (m3) { int c = __builtin_ctzll(m3); wacc += v3 * s_wsl[c]; m3 &= m3 - 1; }
        }
    }
    s_acc[tid] = (a0 + a1) + (a2 + a3);
    s_wacc[tid] = wacc;
    __syncthreads();

    float part = 0.f;
    if (tid < HALF) {
        // this thread's scan p was h*HALF + tid (chunk 0) -> mp/sp still valid
        float d = 0.5f + s_acc[tid] + s_acc[tid + HALF];
        float wtot = s_wacc[tid] + s_wacc[tid + HALF];
        float wself = 0.f;
        unsigned long long m = mp;
        while (m) { int c = __builtin_ctzll(m); wself += s_wsl[c]; m &= m - 1; }
        part = (wtot + 0.5f * wself) * __builtin_amdgcn_rcpf(d);
    }

    for (int off = 32; off > 0; off >>= 1) part += __shfl_down(part, off, 64);
    if (lane == 0) s_red[wave] = part;
    __syncthreads();
    if (tid == 0) {
        float tot = 0.f;
#pragma unroll
        for (int w = 0; w < 6; ++w) tot += s_red[w];
        atomicAdd(out, -tot * (1.0f / (float)BB));
    }
}

extern "C" void kernel_launch(void* const* d_in, const int* in_sizes, int n_in,
                              void* d_out, int out_size, void* d_ws, size_t ws_size,
                              hipStream_t stream) {
    const float* preds = (const float*)d_in[0];       // (384,512) f32
    const float* softlabels = (const float*)d_in[1];  // (384,48) f32
    float* out = (float*)d_out;

    char* ws = (char*)d_ws;
    float* simk    = (float*)(ws + 0);         // 589824
    float* wclass  = (float*)(ws + 589824);    // 192
    uint2* maskbuf = (uint2*)(ws + 590016);    // 384*8 = 3072

    simprep_kernel<<<BB / 2 + 1, 384, 0, stream>>>(preds, softlabels, simk, wclass,
                                                   maskbuf, out);
    mega_kernel<<<BB * 2, 384, 0, stream>>>(simk, softlabels, wclass, maskbuf, out);
}

// Round 11
// 81.636 us; speedup vs baseline: 1.2587x; 1.2587x over previous
//
#include <hip/hip_runtime.h>

// SoftSmoothAP on MI355X. B=384, C=48, D=512. Output: scalar f32 loss = 1 - AP.
//
//   simk[i,q] = <preds_i, preds_q> * 100*log2(e)   (pre-scaled)
//   E[q] = 2^(simk[q] - M),  M = (rowmax+rowmin)/2  (mid-range: no under/overflow)
//   sg(p,q) = sigmoid(100*(sim_q-sim_p)) = E[q] / (E[q] + E[p])
//           -> inner loop = add + rcp + fmac (1 trans op, was 2)
//   denom[i,p] = 0.5 + sum_all_q sg   (diag q==p -> Ep*rcp(2Ep) = 0.5)
//   loss = 1 - (1/B) sum_{i,c} sl[i,c]*w[c] *
//            sum_{p in P_c} (0.5 + sum_{q in P_c} sg) / denom[i,p]
//
// R11: revert R10's mask fusion (divergent while-loops flooded the VALU pipe;
// 77us measured). Keep R9 phase-B lists. New: E-form sigmoid (halves trans,
// cuts main-pipe 1/3) + 576-thr mega blocks (27 waves/CU, was 18) + sim
// reshaped to 576 blocks.

#define BB 384
#define CC 48
#define DD 512
#define HALF 192
#define MAXE 3072
#define SCALE 144.269504089f  // 100 * log2(e)

__device__ __forceinline__ float sigE(float Eq, float Ep) {
    return Eq * __builtin_amdgcn_rcpf(Eq + Ep);
}

// ---- 1. sim (blocks 0..575: i-pair x q-third) + prep (block 576) -------------
__global__ __launch_bounds__(256) void simprep_kernel(
    const float* __restrict__ preds, const float* __restrict__ softlabels,
    float* __restrict__ simk, float* __restrict__ wclass,
    int* __restrict__ cls_idx, int* __restrict__ cls_off,
    int* __restrict__ flat_pack, int* __restrict__ ent_lo, int* __restrict__ ent_hi,
    int* __restrict__ nE3, float* __restrict__ out) {
    int tid = threadIdx.x;
    int wave = tid >> 6, lane = tid & 63;

    if (blockIdx.x < 576) {
        int ip = blockIdx.x / 3;   // i-pair
        int qt = blockIdx.x % 3;   // q-third
        int i0 = ip * 2;
        __shared__ __align__(16) float4 rows[2 * DD / 4];  // 256 x float4
        const float4* src = reinterpret_cast<const float4*>(preds + i0 * DD);
        rows[tid] = src[tid];
        __syncthreads();
        int r = tid >> 7;                 // row 0/1
        int q = qt * 128 + (tid & 127);   // this third's q
        const float4* pq = reinterpret_cast<const float4*>(preds + q * DD);
        const float4* pr = rows + r * (DD / 4);
        float a = 0.f;
#pragma unroll 8
        for (int d4 = 0; d4 < DD / 4; ++d4) {
            float4 b = pq[d4];
            float4 rr = pr[d4];
            a += rr.x * b.x + rr.y * b.y + rr.z * b.z + rr.w * b.w;
        }
        simk[(i0 + r) * BB + q] = a * SCALE;
    } else {
        // ---- prep (256 thr, 4 waves): bitmask transpose -> class lists ----
        __shared__ unsigned int s_mlo[BB];
        __shared__ unsigned int s_mhi[BB];
        __shared__ int s_cnt[CC];
        __shared__ int s_lcnt[CC];
        __shared__ int s_soff[CC + 1];
        __shared__ int s_loff[CC + 1];
        __shared__ int s_hoff[CC + 1];

        for (int p = tid; p < BB; p += 256) {
            const float4* row = reinterpret_cast<const float4*>(softlabels + p * CC);
            unsigned int lo = 0, hi = 0;
#pragma unroll
            for (int v = 0; v < 12; ++v) {
                float4 x = row[v];
                unsigned int b = (x.x > 0.f ? 1u : 0u) | (x.y > 0.f ? 2u : 0u) |
                                 (x.z > 0.f ? 4u : 0u) | (x.w > 0.f ? 8u : 0u);
                if (v < 8) lo |= b << (4 * v);
                else       hi |= b << (4 * (v - 8));
            }
            s_mlo[p] = lo;
            s_mhi[p] = hi;
        }
        __syncthreads();

        for (int c = wave; c < CC; c += 4) {
            int base = 0, lbase = 0;
#pragma unroll
            for (int t = 0; t < BB / 64; ++t) {
                int p = t * 64 + lane;
                bool pos = ((c < 32 ? (s_mlo[p] >> c) : (s_mhi[p] >> (c - 32))) & 1u) != 0u;
                unsigned long long m = __ballot(pos);
                if (pos)
                    cls_idx[c * BB + base + __popcll(m & ((1ull << lane) - 1ull))] = p;
                base += __popcll(m);
                if (t < 3) lbase += __popcll(m);  // p<192 <=> t<3
            }
            if (lane == 0) {
                s_cnt[c] = base;
                s_lcnt[c] = lbase;
                wclass[c] = (base >= 4) ? (1.0f / (float)base) : 0.0f;
            }
        }
        __syncthreads();
        if (tid < 64) {
            int a = (tid < CC) ? s_cnt[tid] : 0;
            int l = (tid < CC) ? s_lcnt[tid] : 0;
            int hg = a - l;
#pragma unroll
            for (int d = 1; d < 64; d <<= 1) {
                int oa = __shfl_up(a, d, 64);
                int ol = __shfl_up(l, d, 64);
                int oh = __shfl_up(hg, d, 64);
                if (tid >= d) { a += oa; l += ol; hg += oh; }
            }
            if (tid < CC) { s_soff[tid + 1] = a; s_loff[tid + 1] = l; s_hoff[tid + 1] = hg; }
            if (tid == 0) { s_soff[0] = 0; s_loff[0] = 0; s_hoff[0] = 0; }
            if (tid == CC - 1) { nE3[0] = a; nE3[1] = l; nE3[2] = hg; }
        }
        __syncthreads();
        if (tid <= CC) cls_off[tid] = s_soff[tid];
        for (int c = wave; c < CC; c += 4) {
            int off = s_soff[c], cnt = s_cnt[c], L = s_lcnt[c];
            int lo = s_loff[c], ho = s_hoff[c];
            for (int k = lane; k < cnt; k += 64) {
                int p = cls_idx[c * BB + k];
                int pk = (c << 16) | p;
                flat_pack[off + k] = pk;
                if (k < L) ent_lo[lo + k] = pk;
                else       ent_hi[ho + (k - L)] = pk;
            }
        }
        if (tid == 0) out[0] = 1.0f;
    }
}

// ---- 2. mega768x576: E-form denom (3 thr/p) + phaseB, block = (i, h) ---------
__global__ __launch_bounds__(576) void mega_kernel(
    const float* __restrict__ simk, const float* __restrict__ softlabels,
    const float* __restrict__ wclass, const int* __restrict__ cls_off,
    const int* __restrict__ flat_pack, const int* __restrict__ ent_lo,
    const int* __restrict__ ent_hi, const int* __restrict__ nE3,
    float* __restrict__ out) {
    int i = blockIdx.x >> 1, h = blockIdx.x & 1;
    int tid = threadIdx.x;
    int wave = tid >> 6, lane = tid & 63;

    __shared__ __align__(16) float s_E[BB];
    __shared__ float s_sim[BB];
    __shared__ float s_part[576];
    __shared__ float s_inv[HALF];
    __shared__ float s_wsl[CC];
    __shared__ int s_offs[CC + 1];
    __shared__ unsigned short s_pl[MAXE];
    __shared__ float s_red[9];
    __shared__ float s_mm[12];  // [0..5] wave maxes, [6..11] wave mins

    int nE = nE3[0];
    if (tid < BB) s_sim[tid] = simk[i * BB + tid];
    if (tid < CC) s_wsl[tid] = wclass[tid] * softlabels[i * CC + tid];
    if (tid <= CC) s_offs[tid] = cls_off[tid];
    for (int e = tid; e < nE; e += 576) s_pl[e] = (unsigned short)(flat_pack[e] & 0xFFFF);
    __syncthreads();

    // row max/min -> mid-range M -> E = 2^(sim - M)
    if (tid < BB) {
        float v = s_sim[tid];
        float mx = v, mn = v;
#pragma unroll
        for (int off = 32; off > 0; off >>= 1) {
            mx = fmaxf(mx, __shfl_xor(mx, off, 64));
            mn = fminf(mn, __shfl_xor(mn, off, 64));
        }
        if (lane == 0) { s_mm[wave] = mx; s_mm[6 + wave] = mn; }
    }
    __syncthreads();
    {
        float mx = s_mm[0], mn = s_mm[6];
#pragma unroll
        for (int w = 1; w < 6; ++w) {
            mx = fmaxf(mx, s_mm[w]);
            mn = fminf(mn, s_mm[6 + w]);
        }
        float M = 0.5f * (mx + mn);
        if (tid < BB) s_E[tid] = __builtin_amdgcn_exp2f(s_sim[tid] - M);
    }
    __syncthreads();

    // --- denominators: 3 threads/p (128 q each), 8 rcp chains ---
    {
        int pl = tid % HALF;     // lane-contiguous p
        int third = tid / HALF;  // wave-uniform q-third
        float Ep = s_E[h * HALF + pl];
        const float4* sv = reinterpret_cast<const float4*>(s_E + third * 128);
        float a0 = 0.f, a1 = 0.f, a2 = 0.f, a3 = 0.f;
        float a4 = 0.f, a5 = 0.f, a6 = 0.f, a7 = 0.f;
#pragma unroll 4
        for (int t = 0; t < 16; ++t) {
            float4 v0 = sv[2 * t];      // same-address broadcast reads
            float4 v1 = sv[2 * t + 1];
            a0 += sigE(v0.x, Ep);
            a1 += sigE(v0.y, Ep);
            a2 += sigE(v0.z, Ep);
            a3 += sigE(v0.w, Ep);
            a4 += sigE(v1.x, Ep);
            a5 += sigE(v1.y, Ep);
            a6 += sigE(v1.z, Ep);
            a7 += sigE(v1.w, Ep);
        }
        s_part[tid] = ((a0 + a1) + (a2 + a3)) + ((a4 + a5) + (a6 + a7));
    }
    __syncthreads();
    if (tid < HALF) {
        float d = 0.5f + s_part[tid] + s_part[tid + HALF] + s_part[tid + 2 * HALF];
        s_inv[tid] = __builtin_amdgcn_rcpf(d);
    }
    __syncthreads();

    // --- positive-rank phase over this half's entries ---
    const int* ent = h ? ent_hi : ent_lo;
    int n = nE3[1 + h];
    float part = 0.f;
    for (int e = tid; e < n; e += 576) {
        int pk = ent[e];
        int c = pk >> 16, p = pk & 0xFFFF;
        int off = s_offs[c], m = s_offs[c + 1] - off;
        float Ep = s_E[p];
        float b0 = 0.f, b1 = 0.f, b2 = 0.f, b3 = 0.f;
        int k = 0;
        for (; k + 3 < m; k += 4) {
            b0 += sigE(s_E[s_pl[off + k]], Ep);
            b1 += sigE(s_E[s_pl[off + k + 1]], Ep);
            b2 += sigE(s_E[s_pl[off + k + 2]], Ep);
            b3 += sigE(s_E[s_pl[off + k + 3]], Ep);
        }
        for (; k < m; ++k) b0 += sigE(s_E[s_pl[off + k]], Ep);
        float s = (b0 + b1) + (b2 + b3);
        // s includes q==p (=0.5): numerator = 0.5 + s
        part += (0.5f + s) * s_inv[p - h * HALF] * s_wsl[c];
    }

    for (int off = 32; off > 0; off >>= 1) part += __shfl_down(part, off, 64);
    if (lane == 0) s_red[wave] = part;
    __syncthreads();
    if (tid == 0) {
        float tot = 0.f;
#pragma unroll
        for (int w = 0; w < 9; ++w) tot += s_red[w];
        atomicAdd(out, -tot * (1.0f / (float)BB));
    }
}

extern "C" void kernel_launch(void* const* d_in, const int* in_sizes, int n_in,
                              void* d_out, int out_size, void* d_ws, size_t ws_size,
                              hipStream_t stream) {
    const float* preds = (const float*)d_in[0];       // (384,512) f32
    const float* softlabels = (const float*)d_in[1];  // (384,48) f32
    float* out = (float*)d_out;

    char* ws = (char*)d_ws;
    float* simk     = (float*)(ws + 0);         // 589824
    float* wclass   = (float*)(ws + 589824);    // 192
    int*   cls_off  = (int*)(ws + 590016);      // 256 (49 used)
    int*   cls_idx  = (int*)(ws + 590272);      // 73728
    int*   flat_pk  = (int*)(ws + 664000);      // 12288
    int*   ent_lo   = (int*)(ws + 676288);      // 12288
    int*   ent_hi   = (int*)(ws + 688576);      // 12288
    int*   nE3      = (int*)(ws + 700864);      // 12

    simprep_kernel<<<577, 256, 0, stream>>>(preds, softlabels, simk, wclass,
                                            cls_idx, cls_off, flat_pk,
                                            ent_lo, ent_hi, nE3, out);
    mega_kernel<<<BB * 2, 576, 0, stream>>>(simk, softlabels, wclass, cls_off,
                                            flat_pk, ent_lo, ent_hi, nE3, out);
}

// Round 12
// 55.853 us; speedup vs baseline: 1.8397x; 1.4616x over previous
//
#include <hip/hip_runtime.h>

// SoftSmoothAP on MI355X. B=384, C=48, D=512. Output: scalar f32 loss = 1 - AP.
//
//   simk[i,q] = <preds_i, preds_q> * 100*log2(e)   (pre-scaled)
//   E[q] = 2^(simk[q] - M),  M = (rowmax+rowmin)/2  (mid-range: no under/overflow)
//   sg(p,q) = sigmoid(100*(sim_q-sim_p)) = E[q] / (E[q] + E[p])
//   denom[i,p] = 0.5 + sum_all_q sg   (diag q==p -> Ep*rcp(2Ep) = 0.5)
//   loss = 1 - (1/B) sum_{i,c} sl[i,c]*w[c] *
//            sum_{p in P_c} (0.5 + sum_{q in P_c} sg) / denom[i,p]
//
// R12: sim rebuilt as coalesced tiled A*A^T (R11's per-lane row streaming was
// 46us at 5.6% VALUBusy -- every wave-load split into 64 cache lines). 24x24
// grid of 16x16 tiles, LDS-staged panels, stride-68 padding. Mega = R11.

#define BB 384
#define CC 48
#define DD 512
#define HALF 192
#define MAXE 3072
#define SA 68  // LDS row stride (floats): breaks bank alignment, keeps 16B align
#define SCALE 144.269504089f  // 100 * log2(e)

__device__ __forceinline__ float sigE(float Eq, float Ep) {
    return Eq * __builtin_amdgcn_rcpf(Eq + Ep);
}

// ---- 1. sim tiles (blocks 0..575) + prep (block 576), 256 thr ----------------
__global__ __launch_bounds__(256) void simprep_kernel(
    const float* __restrict__ preds, const float* __restrict__ softlabels,
    float* __restrict__ simk, float* __restrict__ wclass,
    int* __restrict__ cls_idx, int* __restrict__ cls_off,
    int* __restrict__ flat_pack, int* __restrict__ ent_lo, int* __restrict__ ent_hi,
    int* __restrict__ nE3, float* __restrict__ out) {
    int tid = threadIdx.x;
    int wave = tid >> 6, lane = tid & 63;

    if (blockIdx.x < 576) {
        // ---- sim: 16x16 output tile, k-chunked LDS staging, coalesced ----
        int bi = blockIdx.x / 24, bj = blockIdx.x % 24;
        __shared__ __align__(16) float s_a[16 * SA];
        __shared__ __align__(16) float s_b[16 * SA];
        int row = tid >> 4, c4 = tid & 15;  // also (ti, tj) for compute
        const float* pa = preds + (bi * 16 + row) * DD;
        const float* pb = preds + (bj * 16 + row) * DD;
        float acc0 = 0.f, acc1 = 0.f, acc2 = 0.f, acc3 = 0.f;
#pragma unroll
        for (int kc = 0; kc < 8; ++kc) {
            float4 va = *reinterpret_cast<const float4*>(pa + kc * 64 + c4 * 4);
            float4 vb = *reinterpret_cast<const float4*>(pb + kc * 64 + c4 * 4);
            *reinterpret_cast<float4*>(&s_a[row * SA + c4 * 4]) = va;
            *reinterpret_cast<float4*>(&s_b[row * SA + c4 * 4]) = vb;
            __syncthreads();
#pragma unroll
            for (int k4 = 0; k4 < 16; ++k4) {
                float4 av = *reinterpret_cast<const float4*>(&s_a[row * SA + k4 * 4]);
                float4 bv = *reinterpret_cast<const float4*>(&s_b[c4 * SA + k4 * 4]);
                acc0 += av.x * bv.x;
                acc1 += av.y * bv.y;
                acc2 += av.z * bv.z;
                acc3 += av.w * bv.w;
            }
            __syncthreads();
        }
        simk[(bi * 16 + row) * BB + bj * 16 + c4] =
            ((acc0 + acc1) + (acc2 + acc3)) * SCALE;
    } else {
        // ---- prep (256 thr, 4 waves): bitmask transpose -> class lists ----
        __shared__ unsigned int s_mlo[BB];
        __shared__ unsigned int s_mhi[BB];
        __shared__ int s_cnt[CC];
        __shared__ int s_lcnt[CC];
        __shared__ int s_soff[CC + 1];
        __shared__ int s_loff[CC + 1];
        __shared__ int s_hoff[CC + 1];

        for (int p = tid; p < BB; p += 256) {
            const float4* rowp = reinterpret_cast<const float4*>(softlabels + p * CC);
            unsigned int lo = 0, hi = 0;
#pragma unroll
            for (int v = 0; v < 12; ++v) {
                float4 x = rowp[v];
                unsigned int b = (x.x > 0.f ? 1u : 0u) | (x.y > 0.f ? 2u : 0u) |
                                 (x.z > 0.f ? 4u : 0u) | (x.w > 0.f ? 8u : 0u);
                if (v < 8) lo |= b << (4 * v);
                else       hi |= b << (4 * (v - 8));
            }
            s_mlo[p] = lo;
            s_mhi[p] = hi;
        }
        __syncthreads();

        for (int c = wave; c < CC; c += 4) {
            int base = 0, lbase = 0;
#pragma unroll
            for (int t = 0; t < BB / 64; ++t) {
                int p = t * 64 + lane;
                bool pos = ((c < 32 ? (s_mlo[p] >> c) : (s_mhi[p] >> (c - 32))) & 1u) != 0u;
                unsigned long long m = __ballot(pos);
                if (pos)
                    cls_idx[c * BB + base + __popcll(m & ((1ull << lane) - 1ull))] = p;
                base += __popcll(m);
                if (t < 3) lbase += __popcll(m);  // p<192 <=> t<3
            }
            if (lane == 0) {
                s_cnt[c] = base;
                s_lcnt[c] = lbase;
                wclass[c] = (base >= 4) ? (1.0f / (float)base) : 0.0f;
            }
        }
        __syncthreads();
        if (tid < 64) {
            int a = (tid < CC) ? s_cnt[tid] : 0;
            int l = (tid < CC) ? s_lcnt[tid] : 0;
            int hg = a - l;
#pragma unroll
            for (int d = 1; d < 64; d <<= 1) {
                int oa = __shfl_up(a, d, 64);
                int ol = __shfl_up(l, d, 64);
                int oh = __shfl_up(hg, d, 64);
                if (tid >= d) { a += oa; l += ol; hg += oh; }
            }
            if (tid < CC) { s_soff[tid + 1] = a; s_loff[tid + 1] = l; s_hoff[tid + 1] = hg; }
            if (tid == 0) { s_soff[0] = 0; s_loff[0] = 0; s_hoff[0] = 0; }
            if (tid == CC - 1) { nE3[0] = a; nE3[1] = l; nE3[2] = hg; }
        }
        __syncthreads();
        if (tid <= CC) cls_off[tid] = s_soff[tid];
        for (int c = wave; c < CC; c += 4) {
            int off = s_soff[c], cnt = s_cnt[c], L = s_lcnt[c];
            int lo = s_loff[c], ho = s_hoff[c];
            for (int k = lane; k < cnt; k += 64) {
                int p = cls_idx[c * BB + k];
                int pk = (c << 16) | p;
                flat_pack[off + k] = pk;
                if (k < L) ent_lo[lo + k] = pk;
                else       ent_hi[ho + (k - L)] = pk;
            }
        }
        if (tid == 0) out[0] = 1.0f;
    }
}

// ---- 2. mega768x576: E-form denom (3 thr/p) + phaseB, block = (i, h) ---------
__global__ __launch_bounds__(576) void mega_kernel(
    const float* __restrict__ simk, const float* __restrict__ softlabels,
    const float* __restrict__ wclass, const int* __restrict__ cls_off,
    const int* __restrict__ flat_pack, const int* __restrict__ ent_lo,
    const int* __restrict__ ent_hi, const int* __restrict__ nE3,
    float* __restrict__ out) {
    int i = blockIdx.x >> 1, h = blockIdx.x & 1;
    int tid = threadIdx.x;
    int wave = tid >> 6, lane = tid & 63;

    __shared__ __align__(16) float s_E[BB];
    __shared__ float s_sim[BB];
    __shared__ float s_part[576];
    __shared__ float s_inv[HALF];
    __shared__ float s_wsl[CC];
    __shared__ int s_offs[CC + 1];
    __shared__ unsigned short s_pl[MAXE];
    __shared__ float s_red[9];
    __shared__ float s_mm[12];  // [0..5] wave maxes, [6..11] wave mins

    int nE = nE3[0];
    if (tid < BB) s_sim[tid] = simk[i * BB + tid];
    if (tid < CC) s_wsl[tid] = wclass[tid] * softlabels[i * CC + tid];
    if (tid <= CC) s_offs[tid] = cls_off[tid];
    for (int e = tid; e < nE; e += 576) s_pl[e] = (unsigned short)(flat_pack[e] & 0xFFFF);
    __syncthreads();

    // row max/min -> mid-range M -> E = 2^(sim - M)
    if (tid < BB) {
        float v = s_sim[tid];
        float mx = v, mn = v;
#pragma unroll
        for (int off = 32; off > 0; off >>= 1) {
            mx = fmaxf(mx, __shfl_xor(mx, off, 64));
            mn = fminf(mn, __shfl_xor(mn, off, 64));
        }
        if (lane == 0) { s_mm[wave] = mx; s_mm[6 + wave] = mn; }
    }
    __syncthreads();
    {
        float mx = s_mm[0], mn = s_mm[6];
#pragma unroll
        for (int w = 1; w < 6; ++w) {
            mx = fmaxf(mx, s_mm[w]);
            mn = fminf(mn, s_mm[6 + w]);
        }
        float M = 0.5f * (mx + mn);
        if (tid < BB) s_E[tid] = __builtin_amdgcn_exp2f(s_sim[tid] - M);
    }
    __syncthreads();

    // --- denominators: 3 threads/p (128 q each), 8 rcp chains ---
    {
        int pl = tid % HALF;     // lane-contiguous p
        int third = tid / HALF;  // wave-uniform q-third
        float Ep = s_E[h * HALF + pl];
        const float4* sv = reinterpret_cast<const float4*>(s_E + third * 128);
        float a0 = 0.f, a1 = 0.f, a2 = 0.f, a3 = 0.f;
        float a4 = 0.f, a5 = 0.f, a6 = 0.f, a7 = 0.f;
#pragma unroll 4
        for (int t = 0; t < 16; ++t) {
            float4 v0 = sv[2 * t];      // same-address broadcast reads
            float4 v1 = sv[2 * t + 1];
            a0 += sigE(v0.x, Ep);
            a1 += sigE(v0.y, Ep);
            a2 += sigE(v0.z, Ep);
            a3 += sigE(v0.w, Ep);
            a4 += sigE(v1.x, Ep);
            a5 += sigE(v1.y, Ep);
            a6 += sigE(v1.z, Ep);
            a7 += sigE(v1.w, Ep);
        }
        s_part[tid] = ((a0 + a1) + (a2 + a3)) + ((a4 + a5) + (a6 + a7));
    }
    __syncthreads();
    if (tid < HALF) {
        float d = 0.5f + s_part[tid] + s_part[tid + HALF] + s_part[tid + 2 * HALF];
        s_inv[tid] = __builtin_amdgcn_rcpf(d);
    }
    __syncthreads();

    // --- positive-rank phase over this half's entries ---
    const int* ent = h ? ent_hi : ent_lo;
    int n = nE3[1 + h];
    float part = 0.f;
    for (int e = tid; e < n; e += 576) {
        int pk = ent[e];
        int c = pk >> 16, p = pk & 0xFFFF;
        int off = s_offs[c], m = s_offs[c + 1] - off;
        float Ep = s_E[p];
        float b0 = 0.f, b1 = 0.f, b2 = 0.f, b3 = 0.f;
        int k = 0;
        for (; k + 3 < m; k += 4) {
            b0 += sigE(s_E[s_pl[off + k]], Ep);
            b1 += sigE(s_E[s_pl[off + k + 1]], Ep);
            b2 += sigE(s_E[s_pl[off + k + 2]], Ep);
            b3 += sigE(s_E[s_pl[off + k + 3]], Ep);
        }
        for (; k < m; ++k) b0 += sigE(s_E[s_pl[off + k]], Ep);
        float s = (b0 + b1) + (b2 + b3);
        // s includes q==p (=0.5): numerator = 0.5 + s
        part += (0.5f + s) * s_inv[p - h * HALF] * s_wsl[c];
    }

    for (int off = 32; off > 0; off >>= 1) part += __shfl_down(part, off, 64);
    if (lane == 0) s_red[wave] = part;
    __syncthreads();
    if (tid == 0) {
        float tot = 0.f;
#pragma unroll
        for (int w = 0; w < 9; ++w) tot += s_red[w];
        atomicAdd(out, -tot * (1.0f / (float)BB));
    }
}

extern "C" void kernel_launch(void* const* d_in, const int* in_sizes, int n_in,
                              void* d_out, int out_size, void* d_ws, size_t ws_size,
                              hipStream_t stream) {
    const float* preds = (const float*)d_in[0];       // (384,512) f32
    const float* softlabels = (const float*)d_in[1];  // (384,48) f32
    float* out = (float*)d_out;

    char* ws = (char*)d_ws;
    float* simk     = (float*)(ws + 0);         // 589824
    float* wclass   = (float*)(ws + 589824);    // 192
    int*   cls_off  = (int*)(ws + 590016);      // 256 (49 used)
    int*   cls_idx  = (int*)(ws + 590272);      // 73728
    int*   flat_pk  = (int*)(ws + 664000);      // 12288
    int*   ent_lo   = (int*)(ws + 676288);      // 12288
    int*   ent_hi   = (int*)(ws + 688576);      // 12288
    int*   nE3      = (int*)(ws + 700864);      // 12

    simprep_kernel<<<577, 256, 0, stream>>>(preds, softlabels, simk, wclass,
                                            cls_idx, cls_off, flat_pk,
                                            ent_lo, ent_hi, nE3, out);
    mega_kernel<<<BB * 2, 576, 0, stream>>>(simk, softlabels, wclass, cls_off,
                                            flat_pk, ent_lo, ent_hi, nE3, out);
}

// Round 13
// 43.246 us; speedup vs baseline: 2.3761x; 1.2915x over previous
//
#include <hip/hip_runtime.h>

// SoftSmoothAP on MI355X. B=384, C=48, D=512. Output: scalar f32 loss = 1 - AP.
//
//   sim[i,q] = <preds_i, preds_q>;  simk = sim * 100*log2(e)
//   E[q] = 2^(simk[q] - M),  M = (rowmax+rowmin)/2
//   sg(p,q) = sigmoid(100*(sim_q-sim_p)) = E[q] / (E[q] + E[p])
//   denom[i,p] = 0.5 + sum_all_q sg   (self term = 0.5)
//   loss = 1 - (1/B) sum_{i,c} sl[i,c]*w[c] *
//            sum_{p in P_c} (0.5 + sum_{q in P_c} sg) / denom[i,p]
//
// R13: (a) sim = 64x64 register-blocked tiles (4x4/thread), [k][row] LDS
// panels, k split 4-ways into partial buffers (summed in mega). (b) mega
// phase B per-class: lane=p, inner q-loop reads pre-staged s_Eq broadcast
// (no per-lane gathers).

#define BB 384
#define CC 48
#define DD 512
#define HALF 192
#define MAXE 3072
#define SCALE 144.269504089f  // 100 * log2(e)

__device__ __forceinline__ float sigE(float Eq, float Ep) {
    return Eq * __builtin_amdgcn_rcpf(Eq + Ep);
}

// ---- 1. sim tiles (blocks 0..143 = 36 tiles x 4 k-chunks) + prep (block 144) -
__global__ __launch_bounds__(256) void simprep_kernel(
    const float* __restrict__ preds, const float* __restrict__ softlabels,
    float* __restrict__ simpart, float* __restrict__ wclass,
    int* __restrict__ cls_off, unsigned short* __restrict__ plist,
    float* __restrict__ out) {
    int tid = threadIdx.x;

    if (blockIdx.x < 144) {
        int t = blockIdx.x >> 2, kc = blockIdx.x & 3;
        int bi = t / 6, bj = t % 6;
        __shared__ __align__(16) float s_a[128][68];
        __shared__ __align__(16) float s_b[128][68];
        int kbase = kc * 128;
#pragma unroll
        for (int it = 0; it < 8; ++it) {
            int idx = it * 256 + tid;
            int r = idx >> 5;   // 0..63
            int c4 = idx & 31;  // 0..31
            float4 va = *reinterpret_cast<const float4*>(
                preds + (bi * 64 + r) * DD + kbase + c4 * 4);
            float4 vb = *reinterpret_cast<const float4*>(
                preds + (bj * 64 + r) * DD + kbase + c4 * 4);
            s_a[c4 * 4 + 0][r] = va.x; s_a[c4 * 4 + 1][r] = va.y;
            s_a[c4 * 4 + 2][r] = va.z; s_a[c4 * 4 + 3][r] = va.w;
            s_b[c4 * 4 + 0][r] = vb.x; s_b[c4 * 4 + 1][r] = vb.y;
            s_b[c4 * 4 + 2][r] = vb.z; s_b[c4 * 4 + 3][r] = vb.w;
        }
        __syncthreads();
        int ty = tid >> 4, tx = tid & 15;
        float4 acc0 = {0,0,0,0}, acc1 = {0,0,0,0}, acc2 = {0,0,0,0}, acc3 = {0,0,0,0};
#pragma unroll 4
        for (int k = 0; k < 128; ++k) {
            float4 a4 = *reinterpret_cast<const float4*>(&s_a[k][ty * 4]);  // 4-addr bcast
            float4 b4 = *reinterpret_cast<const float4*>(&s_b[k][tx * 4]);  // 2-way: free
            acc0.x += a4.x * b4.x; acc0.y += a4.x * b4.y; acc0.z += a4.x * b4.z; acc0.w += a4.x * b4.w;
            acc1.x += a4.y * b4.x; acc1.y += a4.y * b4.y; acc1.z += a4.y * b4.z; acc1.w += a4.y * b4.w;
            acc2.x += a4.z * b4.x; acc2.y += a4.z * b4.y; acc2.z += a4.z * b4.z; acc2.w += a4.z * b4.w;
            acc3.x += a4.w * b4.x; acc3.y += a4.w * b4.y; acc3.z += a4.w * b4.z; acc3.w += a4.w * b4.w;
        }
        float* dst = simpart + kc * (BB * BB) + (bi * 64 + ty * 4) * BB + bj * 64 + tx * 4;
        *reinterpret_cast<float4*>(dst + 0 * BB) = acc0;
        *reinterpret_cast<float4*>(dst + 1 * BB) = acc1;
        *reinterpret_cast<float4*>(dst + 2 * BB) = acc2;
        *reinterpret_cast<float4*>(dst + 3 * BB) = acc3;
    } else {
        // ---- prep (256 thr, 4 waves): masks -> counts -> scan -> plist ----
        __shared__ unsigned int s_mlo[BB];
        __shared__ unsigned int s_mhi[BB];
        __shared__ int s_cnt[CC];
        __shared__ int s_soff[CC + 1];
        int wave = tid >> 6, lane = tid & 63;

        for (int p = tid; p < BB; p += 256) {
            const float4* rowp = reinterpret_cast<const float4*>(softlabels + p * CC);
            unsigned int lo = 0, hi = 0;
#pragma unroll
            for (int v = 0; v < 12; ++v) {
                float4 x = rowp[v];
                unsigned int b = (x.x > 0.f ? 1u : 0u) | (x.y > 0.f ? 2u : 0u) |
                                 (x.z > 0.f ? 4u : 0u) | (x.w > 0.f ? 8u : 0u);
                if (v < 8) lo |= b << (4 * v);
                else       hi |= b << (4 * (v - 8));
            }
            s_mlo[p] = lo;
            s_mhi[p] = hi;
        }
        __syncthreads();

        for (int c = wave; c < CC; c += 4) {
            int cnt = 0;
#pragma unroll
            for (int t = 0; t < BB / 64; ++t) {
                int p = t * 64 + lane;
                bool pos = ((c < 32 ? (s_mlo[p] >> c) : (s_mhi[p] >> (c - 32))) & 1u) != 0u;
                cnt += __popcll(__ballot(pos));
            }
            if (lane == 0) {
                s_cnt[c] = cnt;
                wclass[c] = (cnt >= 4) ? (1.0f / (float)cnt) : 0.0f;
            }
        }
        __syncthreads();
        if (tid < 64) {
            int v = (tid < CC) ? s_cnt[tid] : 0;
#pragma unroll
            for (int d = 1; d < 64; d <<= 1) {
                int o = __shfl_up(v, d, 64);
                if (tid >= d) v += o;
            }
            if (tid < CC) s_soff[tid + 1] = v;
            if (tid == 0) s_soff[0] = 0;
        }
        __syncthreads();
        if (tid <= CC) cls_off[tid] = s_soff[tid];
        for (int c = wave; c < CC; c += 4) {
            int base = s_soff[c];
#pragma unroll
            for (int t = 0; t < BB / 64; ++t) {
                int p = t * 64 + lane;
                bool pos = ((c < 32 ? (s_mlo[p] >> c) : (s_mhi[p] >> (c - 32))) & 1u) != 0u;
                unsigned long long m = __ballot(pos);
                if (pos)
                    plist[base + __popcll(m & ((1ull << lane) - 1ull))] = (unsigned short)p;
                base += __popcll(m);
            }
        }
        if (tid == 0) out[0] = 1.0f;
    }
}

// ---- 2. mega768x576: E-form denom + per-class phase B, block = (i, h) --------
__global__ __launch_bounds__(576) void mega_kernel(
    const float* __restrict__ simpart, const float* __restrict__ softlabels,
    const float* __restrict__ wclass, const int* __restrict__ cls_off,
    const unsigned short* __restrict__ plist, float* __restrict__ out) {
    int i = blockIdx.x >> 1, h = blockIdx.x & 1;
    int tid = threadIdx.x;
    int wave = tid >> 6, lane = tid & 63;

    __shared__ __align__(16) float s_E[BB];
    __shared__ float s_sim[BB];
    __shared__ float s_part[576];
    __shared__ float s_inv[HALF];
    __shared__ float s_wsl[CC];
    __shared__ int s_off[CC + 1];
    __shared__ unsigned short s_pl[MAXE];
    __shared__ float s_Eq[MAXE];
    __shared__ float s_red[9];
    __shared__ float s_mm[12];

    if (tid < BB) {
        int x = i * BB + tid;
        s_sim[tid] = SCALE * ((simpart[x] + simpart[BB * BB + x]) +
                              (simpart[2 * BB * BB + x] + simpart[3 * BB * BB + x]));
    }
    if (tid < CC) s_wsl[tid] = wclass[tid] * softlabels[i * CC + tid];
    if (tid <= CC) s_off[tid] = cls_off[tid];
    __syncthreads();
    int nE = s_off[CC];
    for (int e = tid; e < nE; e += 576) s_pl[e] = plist[e];

    // row max/min -> mid-range M -> E = 2^(sim - M)
    if (tid < BB) {
        float v = s_sim[tid];
        float mx = v, mn = v;
#pragma unroll
        for (int off = 32; off > 0; off >>= 1) {
            mx = fmaxf(mx, __shfl_xor(mx, off, 64));
            mn = fminf(mn, __shfl_xor(mn, off, 64));
        }
        if (lane == 0) { s_mm[wave] = mx; s_mm[6 + wave] = mn; }
    }
    __syncthreads();
    {
        float mx = s_mm[0], mn = s_mm[6];
#pragma unroll
        for (int w = 1; w < 6; ++w) {
            mx = fmaxf(mx, s_mm[w]);
            mn = fminf(mn, s_mm[6 + w]);
        }
        float M = 0.5f * (mx + mn);
        if (tid < BB) s_E[tid] = __builtin_amdgcn_exp2f(s_sim[tid] - M);
    }
    __syncthreads();
    // stage per-entry Eq (few gathers, once)
    for (int e = tid; e < nE; e += 576) s_Eq[e] = s_E[s_pl[e]];

    // --- denominators: 3 threads/p (128 q each), 8 rcp chains ---
    {
        int pl = tid % HALF;     // lane-contiguous p
        int third = tid / HALF;  // wave-uniform q-third
        float Ep = s_E[h * HALF + pl];
        const float4* sv = reinterpret_cast<const float4*>(s_E + third * 128);
        float a0 = 0.f, a1 = 0.f, a2 = 0.f, a3 = 0.f;
        float a4 = 0.f, a5 = 0.f, a6 = 0.f, a7 = 0.f;
#pragma unroll 4
        for (int t = 0; t < 16; ++t) {
            float4 v0 = sv[2 * t];
            float4 v1 = sv[2 * t + 1];
            a0 += sigE(v0.x, Ep);
            a1 += sigE(v0.y, Ep);
            a2 += sigE(v0.z, Ep);
            a3 += sigE(v0.w, Ep);
            a4 += sigE(v1.x, Ep);
            a5 += sigE(v1.y, Ep);
            a6 += sigE(v1.z, Ep);
            a7 += sigE(v1.w, Ep);
        }
        s_part[tid] = ((a0 + a1) + (a2 + a3)) + ((a4 + a5) + (a6 + a7));
    }
    __syncthreads();
    if (tid < HALF) {
        float d = 0.5f + s_part[tid] + s_part[tid + HALF] + s_part[tid + 2 * HALF];
        s_inv[tid] = __builtin_amdgcn_rcpf(d);
    }
    __syncthreads();

    // --- phase B: per-class, lane = p, q-loop reads s_Eq broadcast ---
    float part = 0.f;
    for (int c = wave; c < CC; c += 9) {
        float wc = s_wsl[c];
        if (wc == 0.f) continue;  // wave-uniform
        int off = s_off[c], m = s_off[c + 1] - off;
        for (int b = 0; b < m; b += 64) {
            int l = b + lane;
            float Ep = 0.f, inv = 0.f;
            if (l < m) {
                int p = s_pl[off + l];
                Ep = s_E[p];
                bool inh = h ? (p >= HALF) : (p < HALF);
                inv = inh ? s_inv[p - h * HALF] : 0.f;
            }
            float b0 = 0.f, b1 = 0.f, b2 = 0.f, b3 = 0.f;
            int j = 0;
            for (; j + 3 < m; j += 4) {
                b0 += sigE(s_Eq[off + j], Ep);
                b1 += sigE(s_Eq[off + j + 1], Ep);
                b2 += sigE(s_Eq[off + j + 2], Ep);
                b3 += sigE(s_Eq[off + j + 3], Ep);
            }
            for (; j < m; ++j) b0 += sigE(s_Eq[off + j], Ep);
            float acc = (b0 + b1) + (b2 + b3);
            // acc includes q==p (=0.5) when inv!=0: numerator = 0.5 + acc
            part += (0.5f + acc) * inv * wc;
        }
    }

    for (int off = 32; off > 0; off >>= 1) part += __shfl_down(part, off, 64);
    if (lane == 0) s_red[wave] = part;
    __syncthreads();
    if (tid == 0) {
        float tot = 0.f;
#pragma unroll
        for (int w = 0; w < 9; ++w) tot += s_red[w];
        atomicAdd(out, -tot * (1.0f / (float)BB));
    }
}

extern "C" void kernel_launch(void* const* d_in, const int* in_sizes, int n_in,
                              void* d_out, int out_size, void* d_ws, size_t ws_size,
                              hipStream_t stream) {
    const float* preds = (const float*)d_in[0];       // (384,512) f32
    const float* softlabels = (const float*)d_in[1];  // (384,48) f32
    float* out = (float*)d_out;

    char* ws = (char*)d_ws;
    float*          simpart = (float*)(ws + 0);        // 4 * 589824 = 2359296
    float*          wclass  = (float*)(ws + 2359296);  // 192
    int*            cls_off = (int*)(ws + 2359488);    // 256 (49 used)
    unsigned short* plist   = (unsigned short*)(ws + 2359744);  // 6144

    simprep_kernel<<<145, 256, 0, stream>>>(preds, softlabels, simpart, wclass,
                                            cls_off, plist, out);
    mega_kernel<<<BB * 2, 576, 0, stream>>>(simpart, softlabels, wclass, cls_off,
                                            plist, out);
}